// Round 2
// baseline (479.950 us; speedup 1.0000x reference)
//
#include <hip/hip_runtime.h>
#include <hip/hip_bf16.h>

typedef __attribute__((ext_vector_type(8))) short short8;
typedef __attribute__((ext_vector_type(4))) float floatx4;

#define BATCH 4
#define SEQ 2048
#define D_MODEL 1024
#define NH 16
#define HD 64

// fp32 -> bf16 round-to-nearest-even
__device__ __forceinline__ unsigned short f2bf(float f) {
    union { float f; unsigned u; } x; x.f = f;
    unsigned r = x.u + 0x7FFFu + ((x.u >> 16) & 1u);
    return (unsigned short)(r >> 16);
}

// ---------------------------------------------------------------------------
// QKV GEMM: out[m][n] = sum_k A[m][k] * W[n][k], A,W fp32, out bf16 head-major.
// 128x128 tile, BK=64, 4 waves x (64x64 via 4x4 MFMA 16x16x32 tiles).
// LDS XOR-swizzled on 16B granules: granule g of row r at r*8 + (g^(r&7)).
// ---------------------------------------------------------------------------
__global__ __launch_bounds__(256, 2)
void gemm_qkv_kernel(const float* __restrict__ A,
                     const float* __restrict__ W0,
                     const float* __restrict__ W1,
                     const float* __restrict__ W2,
                     unsigned short* __restrict__ O0,
                     unsigned short* __restrict__ O1,
                     unsigned short* __restrict__ O2)
{
    const int K = 1024;
    const float* W;
    unsigned short* Out;
    if (blockIdx.z == 0)      { W = W0; Out = O0; }
    else if (blockIdx.z == 1) { W = W1; Out = O1; }
    else                      { W = W2; Out = O2; }

    __shared__ __align__(16) unsigned short As[128 * 64];
    __shared__ __align__(16) unsigned short Bs[128 * 64];

    const int t = threadIdx.x;
    const int wave = t >> 6, lane = t & 63;
    const int lm = lane & 15, lq = lane >> 4;
    const int wrow = (wave >> 1) * 64, wcol = (wave & 1) * 64;
    const int m0 = blockIdx.x * 128, n0 = blockIdx.y * 128;

    floatx4 acc[4][4] = {};

    for (int k0 = 0; k0 < K; k0 += 64) {
        __syncthreads();
#pragma unroll
        for (int rr = 0; rr < 4; rr++) {
            int p = rr * 256 + t;
            int row = p >> 3, g = p & 7;
            const float* pa = A + (size_t)(m0 + row) * K + k0 + g * 8;
            const float* pw = W + (size_t)(n0 + row) * K + k0 + g * 8;
            floatx4 a0 = *(const floatx4*)pa, a1 = *(const floatx4*)(pa + 4);
            floatx4 w0 = *(const floatx4*)pw, w1 = *(const floatx4*)(pw + 4);
            short8 va, vb;
#pragma unroll
            for (int d = 0; d < 4; d++) {
                va[d]     = (short)f2bf(a0[d]);
                va[4 + d] = (short)f2bf(a1[d]);
                vb[d]     = (short)f2bf(w0[d]);
                vb[4 + d] = (short)f2bf(w1[d]);
            }
            int dst = row * 8 + (g ^ (row & 7));
            *(short8*)(As + dst * 8) = va;
            *(short8*)(Bs + dst * 8) = vb;
        }
        __syncthreads();

        short8 af[4][2], bf[4][2];
#pragma unroll
        for (int i = 0; i < 4; i++)
#pragma unroll
            for (int c = 0; c < 2; c++) {
                int ra = wrow + i * 16 + lm;
                int rb = wcol + i * 16 + lm;
                int g = c * 4 + lq;
                af[i][c] = *(const short8*)(As + (ra * 8 + (g ^ (ra & 7))) * 8);
                bf[i][c] = *(const short8*)(Bs + (rb * 8 + (g ^ (rb & 7))) * 8);
            }
#pragma unroll
        for (int i = 0; i < 4; i++)
#pragma unroll
            for (int j = 0; j < 4; j++)
#pragma unroll
                for (int c = 0; c < 2; c++)
                    acc[i][j] = __builtin_amdgcn_mfma_f32_16x16x32_bf16(
                        af[i][c], bf[j][c], acc[i][j], 0, 0, 0);
    }

    // C layout: row=(lane>>4)*4+r, col=lane&15. Scatter bf16 to [B,H,S,64].
#pragma unroll
    for (int i = 0; i < 4; i++)
#pragma unroll
        for (int j = 0; j < 4; j++)
#pragma unroll
            for (int r = 0; r < 4; r++) {
                int gm = m0 + wrow + i * 16 + lq * 4 + r;
                int gn = n0 + wcol + j * 16 + lm;
                int b = gm >> 11, s = gm & 2047;
                int h = gn >> 6, d = gn & 63;
                Out[(((size_t)(b * NH + h) * SEQ + s) << 6) + d] = f2bf(acc[i][j][r]);
            }
}

// ---------------------------------------------------------------------------
// Output projection: A bf16 [8192,1024] row-major, W fp32 [1024,1024] (n,k),
// out fp32 row-major = d_out.
// ---------------------------------------------------------------------------
__global__ __launch_bounds__(256, 2)
void gemm_out_kernel(const unsigned short* __restrict__ Abf,
                     const float* __restrict__ W,
                     float* __restrict__ Out)
{
    const int K = 1024;
    __shared__ __align__(16) unsigned short As[128 * 64];
    __shared__ __align__(16) unsigned short Bs[128 * 64];

    const int t = threadIdx.x;
    const int wave = t >> 6, lane = t & 63;
    const int lm = lane & 15, lq = lane >> 4;
    const int wrow = (wave >> 1) * 64, wcol = (wave & 1) * 64;
    const int m0 = blockIdx.x * 128, n0 = blockIdx.y * 128;

    floatx4 acc[4][4] = {};

    for (int k0 = 0; k0 < K; k0 += 64) {
        __syncthreads();
#pragma unroll
        for (int rr = 0; rr < 4; rr++) {
            int p = rr * 256 + t;
            int row = p >> 3, g = p & 7;
            short8 va = *(const short8*)(Abf + (size_t)(m0 + row) * K + k0 + g * 8);
            const float* pw = W + (size_t)(n0 + row) * K + k0 + g * 8;
            floatx4 w0 = *(const floatx4*)pw, w1 = *(const floatx4*)(pw + 4);
            short8 vb;
#pragma unroll
            for (int d = 0; d < 4; d++) {
                vb[d]     = (short)f2bf(w0[d]);
                vb[4 + d] = (short)f2bf(w1[d]);
            }
            int dst = row * 8 + (g ^ (row & 7));
            *(short8*)(As + dst * 8) = va;
            *(short8*)(Bs + dst * 8) = vb;
        }
        __syncthreads();

        short8 af[4][2], bf[4][2];
#pragma unroll
        for (int i = 0; i < 4; i++)
#pragma unroll
            for (int c = 0; c < 2; c++) {
                int ra = wrow + i * 16 + lm;
                int rb = wcol + i * 16 + lm;
                int g = c * 4 + lq;
                af[i][c] = *(const short8*)(As + (ra * 8 + (g ^ (ra & 7))) * 8);
                bf[i][c] = *(const short8*)(Bs + (rb * 8 + (g ^ (rb & 7))) * 8);
            }
#pragma unroll
        for (int i = 0; i < 4; i++)
#pragma unroll
            for (int j = 0; j < 4; j++)
#pragma unroll
                for (int c = 0; c < 2; c++)
                    acc[i][j] = __builtin_amdgcn_mfma_f32_16x16x32_bf16(
                        af[i][c], bf[j][c], acc[i][j], 0, 0, 0);
    }

#pragma unroll
    for (int i = 0; i < 4; i++)
#pragma unroll
        for (int j = 0; j < 4; j++)
#pragma unroll
            for (int r = 0; r < 4; r++) {
                int gm = m0 + wrow + i * 16 + lq * 4 + r;
                int gn = n0 + wcol + j * 16 + lm;
                Out[(size_t)gm * D_MODEL + gn] = acc[i][j][r];
            }
}

// ---------------------------------------------------------------------------
// Flash attention, module semantics: scale = 1/sqrt(D)=1/32; INVERTED mask
// (only j>i kept; lower triangle incl. diagonal filled -1e9). Processing all
// tiles with literal -1e9 reproduces the uniform fully-masked rows exactly.
// Q/K/V bf16 head-major [B,H,S,64]; O bf16 [B,S,D].
// ---------------------------------------------------------------------------
__global__ __launch_bounds__(256, 2)
void attn_kernel(const unsigned short* __restrict__ Q,
                 const unsigned short* __restrict__ K,
                 const unsigned short* __restrict__ V,
                 unsigned short* __restrict__ O)
{
    __shared__ __align__(16) unsigned short Ks[64 * 64];    // [key][dim] swizzled
    __shared__ __align__(16) unsigned short Vt[64 * 72];    // [dim][key], stride 72
    __shared__ __align__(16) unsigned short Ps[4 * 16 * 72]; // per-wave P

    const int t = threadIdx.x;
    const int wave = t >> 6, lane = t & 63;
    const int lm = lane & 15, lq = lane >> 4;
    const int bh = blockIdx.y;
    const int qrow_base = blockIdx.x * 64 + wave * 16;

    const unsigned short* Qh = Q + (size_t)bh * SEQ * HD;
    const unsigned short* Kh = K + (size_t)bh * SEQ * HD;
    const unsigned short* Vh = V + (size_t)bh * SEQ * HD;

    short8 aq[2];
    {
        int row = qrow_base + lm;
        aq[0] = *(const short8*)(Qh + (size_t)row * HD + lq * 8);
        aq[1] = *(const short8*)(Qh + (size_t)row * HD + 32 + lq * 8);
    }

    floatx4 acc[4] = {};
    floatx4 mrun, lrun;
#pragma unroll
    for (int r = 0; r < 4; r++) { mrun[r] = -1e30f; lrun[r] = 0.f; }

    const float scale = 0.03125f;
    unsigned short* Pw = Ps + wave * 16 * 72;

    for (int kt = 0; kt < SEQ / 64; kt++) {
        __syncthreads();
#pragma unroll
        for (int rr = 0; rr < 2; rr++) {
            int p = rr * 256 + t;
            int row = p >> 3, g = p & 7;
            short8 v = *(const short8*)(Kh + (size_t)(kt * 64 + row) * HD + g * 8);
            *(short8*)(Ks + (row * 8 + (g ^ (row & 7))) * 8) = v;
        }
        {
            int key = t >> 2, dbase = (t & 3) * 16;
            const unsigned short* src = Vh + (size_t)(kt * 64 + key) * HD + dbase;
            short8 v0 = *(const short8*)(src);
            short8 v1 = *(const short8*)(src + 8);
#pragma unroll
            for (int dd = 0; dd < 8; dd++) {
                Vt[(dbase + dd) * 72 + key]     = (unsigned short)v0[dd];
                Vt[(dbase + 8 + dd) * 72 + key] = (unsigned short)v1[dd];
            }
        }
        __syncthreads();

        floatx4 sv[4];
#pragma unroll
        for (int j = 0; j < 4; j++) {
            floatx4 sc = {};
#pragma unroll
            for (int c = 0; c < 2; c++) {
                int row = j * 16 + lm;
                int g = c * 4 + lq;
                short8 kf = *(const short8*)(Ks + (row * 8 + (g ^ (row & 7))) * 8);
                sc = __builtin_amdgcn_mfma_f32_16x16x32_bf16(aq[c], kf, sc, 0, 0, 0);
            }
            int kj = kt * 64 + j * 16 + lm;
#pragma unroll
            for (int r = 0; r < 4; r++) {
                int qi = qrow_base + lq * 4 + r;
                sv[j][r] = (kj > qi) ? sc[r] * scale : -1e9f;
            }
        }

        floatx4 rm = sv[0];
#pragma unroll
        for (int j = 1; j < 4; j++)
#pragma unroll
            for (int r = 0; r < 4; r++) rm[r] = fmaxf(rm[r], sv[j][r]);
#pragma unroll
        for (int off = 1; off < 16; off <<= 1)
#pragma unroll
            for (int r = 0; r < 4; r++) rm[r] = fmaxf(rm[r], __shfl_xor(rm[r], off));

        floatx4 mnew, alpha, rs;
#pragma unroll
        for (int r = 0; r < 4; r++) {
            mnew[r] = fmaxf(mrun[r], rm[r]);
            alpha[r] = __expf(mrun[r] - mnew[r]);
            rs[r] = 0.f;
        }
#pragma unroll
        for (int j = 0; j < 4; j++)
#pragma unroll
            for (int r = 0; r < 4; r++) {
                float p = __expf(sv[j][r] - mnew[r]);
                sv[j][r] = p;
                rs[r] += p;
            }
#pragma unroll
        for (int off = 1; off < 16; off <<= 1)
#pragma unroll
            for (int r = 0; r < 4; r++) rs[r] += __shfl_xor(rs[r], off);
#pragma unroll
        for (int r = 0; r < 4; r++) {
            lrun[r] = lrun[r] * alpha[r] + rs[r];
            mrun[r] = mnew[r];
        }
#pragma unroll
        for (int jd = 0; jd < 4; jd++)
#pragma unroll
            for (int r = 0; r < 4; r++) acc[jd][r] *= alpha[r];

        // P: C layout -> A layout via per-wave LDS region (same-wave DS order)
#pragma unroll
        for (int j = 0; j < 4; j++)
#pragma unroll
            for (int r = 0; r < 4; r++)
                Pw[(lq * 4 + r) * 72 + j * 16 + lm] = f2bf(sv[j][r]);

#pragma unroll
        for (int c = 0; c < 2; c++) {
            short8 pf = *(const short8*)(Pw + lm * 72 + c * 32 + lq * 8);
#pragma unroll
            for (int jd = 0; jd < 4; jd++) {
                short8 vf = *(const short8*)(Vt + (jd * 16 + lm) * 72 + c * 32 + lq * 8);
                acc[jd] = __builtin_amdgcn_mfma_f32_16x16x32_bf16(pf, vf, acc[jd], 0, 0, 0);
            }
        }
    }

    const int b = bh >> 4, h = bh & 15;
#pragma unroll
    for (int jd = 0; jd < 4; jd++)
#pragma unroll
        for (int r = 0; r < 4; r++) {
            int qi = qrow_base + lq * 4 + r;
            int dim = jd * 16 + lm;
            O[(size_t)(b * SEQ + qi) * D_MODEL + h * HD + dim] = f2bf(acc[jd][r] / lrun[r]);
        }
}

extern "C" void kernel_launch(void* const* d_in, const int* in_sizes, int n_in,
                              void* d_out, int out_size, void* d_ws, size_t ws_size,
                              hipStream_t stream) {
    const float* x  = (const float*)d_in[0];
    const float* wq = (const float*)d_in[1];
    const float* wk = (const float*)d_in[2];
    const float* wv = (const float*)d_in[3];
    const float* wo = (const float*)d_in[4];

    const size_t elems = (size_t)BATCH * SEQ * D_MODEL;  // 8388608
    unsigned short* Qb = (unsigned short*)d_ws;
    unsigned short* Kb = Qb + elems;
    unsigned short* Vb = Kb + elems;
    unsigned short* Ob = Vb + elems;

    dim3 g1(64, 8, 3);
    gemm_qkv_kernel<<<g1, 256, 0, stream>>>(x, wq, wk, wv, Qb, Kb, Vb);

    dim3 g2(SEQ / 64, BATCH * NH, 1);
    attn_kernel<<<g2, 256, 0, stream>>>(Qb, Kb, Vb, Ob);

    dim3 g3(64, 8, 1);
    gemm_out_kernel<<<g3, 256, 0, stream>>>(Ob, wo, (float*)d_out);
}

// Round 4
// 392.006 us; speedup vs baseline: 1.2243x; 1.2243x over previous
//
#include <hip/hip_runtime.h>
#include <hip/hip_bf16.h>

typedef __attribute__((ext_vector_type(8))) short short8;
typedef __attribute__((ext_vector_type(4))) short bfx4;
typedef __attribute__((ext_vector_type(4))) float floatx4;
typedef __attribute__((ext_vector_type(4))) __fp16 h4_t;
typedef __attribute__((ext_vector_type(2))) __fp16 h2_t;
typedef __attribute__((ext_vector_type(8))) __fp16 h8_t;

#define BATCH 4
#define SEQ 2048
#define D_MODEL 1024
#define NH 16
#define HD 64

// fp32 -> bf16 round-to-nearest-even
__device__ __forceinline__ unsigned short f2bf(float f) {
    union { float f; unsigned u; } x; x.f = f;
    unsigned r = x.u + 0x7FFFu + ((x.u >> 16) & 1u);
    return (unsigned short)(r >> 16);
}
__device__ __forceinline__ unsigned short f2h(float f) {
    union { __fp16 h; unsigned short u; } x;
    x.h = (__fp16)f;
    return x.u;
}

// ---------------------------------------------------------------------------
// QKV GEMM: out[m][n] = sum_k A[m][k]*W[n][k]; A,W fp32 in, out bf16 (Q,K
// head-major [b,h,s,d]) or f16 transposed [b,h,d,s] for V (z==2).
// ---------------------------------------------------------------------------
__global__ __launch_bounds__(256, 2)
void gemm_qkv_kernel(const float* __restrict__ A,
                     const float* __restrict__ W0,
                     const float* __restrict__ W1,
                     const float* __restrict__ W2,
                     unsigned short* __restrict__ O0,
                     unsigned short* __restrict__ O1,
                     unsigned short* __restrict__ O2)
{
    const int K = 1024;
    const float* W;
    unsigned short* Out;
    if (blockIdx.z == 0)      { W = W0; Out = O0; }
    else if (blockIdx.z == 1) { W = W1; Out = O1; }
    else                      { W = W2; Out = O2; }

    __shared__ __align__(16) unsigned short As[128 * 64];
    __shared__ __align__(16) unsigned short Bs[128 * 64];

    const int t = threadIdx.x;
    const int wave = t >> 6, lane = t & 63;
    const int lm = lane & 15, lq = lane >> 4;
    const int wrow = (wave >> 1) * 64, wcol = (wave & 1) * 64;
    const int m0 = blockIdx.x * 128, n0 = blockIdx.y * 128;

    floatx4 acc[4][4] = {};

    for (int k0 = 0; k0 < K; k0 += 64) {
        __syncthreads();
#pragma unroll
        for (int rr = 0; rr < 4; rr++) {
            int p = rr * 256 + t;
            int row = p >> 3, g = p & 7;
            const float* pa = A + (size_t)(m0 + row) * K + k0 + g * 8;
            const float* pw = W + (size_t)(n0 + row) * K + k0 + g * 8;
            floatx4 a0 = *(const floatx4*)pa, a1 = *(const floatx4*)(pa + 4);
            floatx4 w0 = *(const floatx4*)pw, w1 = *(const floatx4*)(pw + 4);
            short8 va, vb;
#pragma unroll
            for (int d = 0; d < 4; d++) {
                va[d]     = (short)f2bf(a0[d]);
                va[4 + d] = (short)f2bf(a1[d]);
                vb[d]     = (short)f2bf(w0[d]);
                vb[4 + d] = (short)f2bf(w1[d]);
            }
            int dst = row * 8 + (g ^ (row & 7));
            *(short8*)(As + dst * 8) = va;
            *(short8*)(Bs + dst * 8) = vb;
        }
        __syncthreads();

        short8 af[4][2], bf[4][2];
#pragma unroll
        for (int i = 0; i < 4; i++)
#pragma unroll
            for (int c = 0; c < 2; c++) {
                int ra = wrow + i * 16 + lm;
                int rb = wcol + i * 16 + lm;
                int g = c * 4 + lq;
                af[i][c] = *(const short8*)(As + (ra * 8 + (g ^ (ra & 7))) * 8);
                bf[i][c] = *(const short8*)(Bs + (rb * 8 + (g ^ (rb & 7))) * 8);
            }
#pragma unroll
        for (int i = 0; i < 4; i++)
#pragma unroll
            for (int j = 0; j < 4; j++)
#pragma unroll
                for (int c = 0; c < 2; c++)
                    acc[i][j] = __builtin_amdgcn_mfma_f32_16x16x32_bf16(
                        af[i][c], bf[j][c], acc[i][j], 0, 0, 0);
    }

    const int zi = blockIdx.z;
#pragma unroll
    for (int i = 0; i < 4; i++)
#pragma unroll
        for (int j = 0; j < 4; j++)
#pragma unroll
            for (int r = 0; r < 4; r++) {
                int gm = m0 + wrow + i * 16 + lq * 4 + r;
                int gn = n0 + wcol + j * 16 + lm;
                int b = gm >> 11, s = gm & 2047;
                int h = gn >> 6, d = gn & 63;
                if (zi == 2) {
                    // V: f16, transposed [b,h,d,s]
                    Out[((size_t)(b * NH + h) * HD + d) * SEQ + s] = f2h(acc[i][j][r]);
                } else {
                    Out[((size_t)(b * NH + h) * SEQ + s) * HD + d] = f2bf(acc[i][j][r]);
                }
            }
}

// ---------------------------------------------------------------------------
// Output projection: A bf16 [8192,1024] row-major, W fp32, out fp32 = d_out.
// ---------------------------------------------------------------------------
__global__ __launch_bounds__(256, 2)
void gemm_out_kernel(const unsigned short* __restrict__ Abf,
                     const float* __restrict__ W,
                     float* __restrict__ Out)
{
    const int K = 1024;
    __shared__ __align__(16) unsigned short As[128 * 64];
    __shared__ __align__(16) unsigned short Bs[128 * 64];

    const int t = threadIdx.x;
    const int wave = t >> 6, lane = t & 63;
    const int lm = lane & 15, lq = lane >> 4;
    const int wrow = (wave >> 1) * 64, wcol = (wave & 1) * 64;
    const int m0 = blockIdx.x * 128, n0 = blockIdx.y * 128;

    floatx4 acc[4][4] = {};

    for (int k0 = 0; k0 < K; k0 += 64) {
        __syncthreads();
#pragma unroll
        for (int rr = 0; rr < 4; rr++) {
            int p = rr * 256 + t;
            int row = p >> 3, g = p & 7;
            short8 va = *(const short8*)(Abf + (size_t)(m0 + row) * K + k0 + g * 8);
            const float* pw = W + (size_t)(n0 + row) * K + k0 + g * 8;
            floatx4 w0 = *(const floatx4*)pw, w1 = *(const floatx4*)(pw + 4);
            short8 vb;
#pragma unroll
            for (int d = 0; d < 4; d++) {
                vb[d]     = (short)f2bf(w0[d]);
                vb[4 + d] = (short)f2bf(w1[d]);
            }
            int dst = row * 8 + (g ^ (row & 7));
            *(short8*)(As + dst * 8) = va;
            *(short8*)(Bs + dst * 8) = vb;
        }
        __syncthreads();

        short8 af[4][2], bf[4][2];
#pragma unroll
        for (int i = 0; i < 4; i++)
#pragma unroll
            for (int c = 0; c < 2; c++) {
                int ra = wrow + i * 16 + lm;
                int rb = wcol + i * 16 + lm;
                int g = c * 4 + lq;
                af[i][c] = *(const short8*)(As + (ra * 8 + (g ^ (ra & 7))) * 8);
                bf[i][c] = *(const short8*)(Bs + (rb * 8 + (g ^ (rb & 7))) * 8);
            }
#pragma unroll
        for (int i = 0; i < 4; i++)
#pragma unroll
            for (int j = 0; j < 4; j++)
#pragma unroll
                for (int c = 0; c < 2; c++)
                    acc[i][j] = __builtin_amdgcn_mfma_f32_16x16x32_bf16(
                        af[i][c], bf[j][c], acc[i][j], 0, 0, 0);
    }

#pragma unroll
    for (int i = 0; i < 4; i++)
#pragma unroll
        for (int j = 0; j < 4; j++)
#pragma unroll
            for (int r = 0; r < 4; r++) {
                int gm = m0 + wrow + i * 16 + lq * 4 + r;
                int gn = n0 + wcol + j * 16 + lm;
                Out[(size_t)gm * D_MODEL + gn] = acc[i][j][r];
            }
}

// ---------------------------------------------------------------------------
// Flash attention, S^T formulation. Inverted mask (keep kj > qi), scale=1/32
// folded into the exponent (exact: 1/32 and -3.2e10 are exact fp32).
// Block = 4 waves; wave w owns 16 q rows; key tiles of 64, kt descending
// from 31 to blockIdx.x (tiles < blockIdx.x are fully masked -> exp == 0
// exactly, matching the fp32 reference). Row 2047 fixed by row2047_kernel.
// Q,K bf16 [b,h,s,d]; V f16 [b,h,d,s]; O bf16 [b,s,1024].
// ---------------------------------------------------------------------------
__global__ __launch_bounds__(256, 3)
void attn_kernel(const unsigned short* __restrict__ Q,
                 const unsigned short* __restrict__ K,
                 const unsigned short* __restrict__ V,
                 unsigned short* __restrict__ O)
{
    __shared__ __align__(16) unsigned short Ks[64 * 64];  // [key][d] swizzled bf16
    __shared__ __align__(16) unsigned short Vs[64 * 64];  // [d][key] swizzled f16

    const int t = threadIdx.x;
    const int wave = t >> 6, lane = t & 63;
    const int lm = lane & 15, lq = lane >> 4;
    const int bh = blockIdx.y;
    const int qbase = blockIdx.x * 64 + wave * 16;
    const int qi = qbase + lm;              // this lane's query row

    const unsigned short* Qh = Q + (size_t)bh * SEQ * HD;
    const unsigned short* Kh = K + (size_t)bh * SEQ * HD;
    const unsigned short* Vh = V + (size_t)bh * HD * SEQ;  // [d][s]

    // Q as B-operand of 16x16x32: lane holds Q[q=lm][d = c*32 + lq*8 + j]
    short8 bq[2];
    bq[0] = *(const short8*)(Qh + (size_t)qi * HD + lq * 8);
    bq[1] = *(const short8*)(Qh + (size_t)qi * HD + 32 + lq * 8);

    // acc[jd][r] = O^T[d = jd*16 + lq*4 + r][q = lm]
    floatx4 acc[4] = {};
    float m_run = -3.2e10f;   // unscaled masked fill (== -1e9 * 32, exact)
    float l_run = 0.f;
    const float kA = 0.04508422002778011f;  // log2(e)/32

    const int kt_min = blockIdx.x;
    for (int kt = 31; kt >= kt_min; kt--) {
        __syncthreads();
        // stage K tile [key][d], 16B-granule XOR swizzle
#pragma unroll
        for (int rr = 0; rr < 2; rr++) {
            int p = rr * 256 + t;
            int row = p >> 3, g = p & 7;
            short8 v = *(const short8*)(Kh + (size_t)(kt * 64 + row) * HD + g * 8);
            *(short8*)(Ks + (row * 8 + (g ^ (row & 7))) * 8) = v;
        }
        // stage V^T tile [d][key] (already transposed in global)
#pragma unroll
        for (int rr = 0; rr < 2; rr++) {
            int p = rr * 256 + t;
            int row = p >> 3, g = p & 7;
            short8 v = *(const short8*)(Vh + (size_t)row * SEQ + kt * 64 + g * 8);
            *(short8*)(Vs + (row * 8 + (g ^ (row & 7))) * 8) = v;
        }
        __syncthreads();

        // S^T[key][q]: A = K[key][d], B = Q[q][d]
        floatx4 sv[4];
#pragma unroll
        for (int jt = 0; jt < 4; jt++) {
            floatx4 sc = {};
#pragma unroll
            for (int c = 0; c < 2; c++) {
                int row = jt * 16 + lm;
                int g = c * 4 + lq;
                short8 kf = *(const short8*)(Ks + (row * 8 + (g ^ (row & 7))) * 8);
                sc = __builtin_amdgcn_mfma_f32_16x16x32_bf16(kf, bq[c], sc, 0, 0, 0);
            }
            sv[jt] = sc;
        }

        // mask only on the single partial tile
        if (kt == kt_min) {
#pragma unroll
            for (int jt = 0; jt < 4; jt++)
#pragma unroll
                for (int r = 0; r < 4; r++) {
                    int kj = kt * 64 + jt * 16 + lq * 4 + r;
                    if (!(kj > qi)) sv[jt][r] = -3.2e10f;
                }
        }

        // online softmax over this lane's 16 keys + quad shuffles (same q)
        float rm = -3.2e10f;
#pragma unroll
        for (int jt = 0; jt < 4; jt++)
#pragma unroll
            for (int r = 0; r < 4; r++) rm = fmaxf(rm, sv[jt][r]);
        rm = fmaxf(rm, __shfl_xor(rm, 16));
        rm = fmaxf(rm, __shfl_xor(rm, 32));

        float mnew = fmaxf(m_run, rm);
        float alpha = exp2f((m_run - mnew) * kA);
        m_run = mnew;

        float rs = 0.f;
#pragma unroll
        for (int jt = 0; jt < 4; jt++)
#pragma unroll
            for (int r = 0; r < 4; r++) {
                float p = exp2f((sv[jt][r] - mnew) * kA);
                sv[jt][r] = p;
                rs += p;
            }
        rs += __shfl_xor(rs, 16);
        rs += __shfl_xor(rs, 32);
        l_run = l_run * alpha + rs;

#pragma unroll
        for (int jd = 0; jd < 4; jd++)
#pragma unroll
            for (int r = 0; r < 4; r++) acc[jd][r] *= alpha;

        // PV: O^T[d][q] += V^T[d][key] * P^T[key][q], 16x16x16 f16 MFMA,
        // P^T comes straight from sv registers (C-layout == B-operand, K=16)
#pragma unroll
        for (int c = 0; c < 4; c++) {
            h2_t p01 = __builtin_amdgcn_cvt_pkrtz(sv[c][0], sv[c][1]);
            h2_t p23 = __builtin_amdgcn_cvt_pkrtz(sv[c][2], sv[c][3]);
            h4_t pf;
            pf[0] = p01[0]; pf[1] = p01[1]; pf[2] = p23[0]; pf[3] = p23[1];
#pragma unroll
            for (int jd = 0; jd < 4; jd++) {
                int row = jd * 16 + lm;
                int g = c * 2 + (lq >> 1);
                int addr = (row * 8 + (g ^ (row & 7))) * 8 + (lq & 1) * 4;
                h4_t vf = *(const h4_t*)((const __fp16*)Vs + addr);
                acc[jd] = __builtin_amdgcn_mfma_f32_16x16x16f16(vf, pf, acc[jd], 0, 0, 0);
            }
        }
    }

    // epilogue: O[b][s=qi][h*64 + d], 4 consecutive d per store (8B)
    const int b = bh >> 4, h = bh & 15;
    float inv = 1.0f / l_run;
#pragma unroll
    for (int jd = 0; jd < 4; jd++) {
        bfx4 o;
#pragma unroll
        for (int r = 0; r < 4; r++) o[r] = (short)f2bf(acc[jd][r] * inv);
        *(bfx4*)(O + (size_t)(b * SEQ + qi) * D_MODEL + h * HD + jd * 16 + lq * 4) = o;
    }
}

// ---------------------------------------------------------------------------
// Row 2047 is fully masked -> uniform softmax over ALL keys -> mean of V.
// ---------------------------------------------------------------------------
__global__ __launch_bounds__(256, 2)
void row2047_kernel(const unsigned short* __restrict__ V,
                    unsigned short* __restrict__ O)
{
    __shared__ float red[256];
    const int bh = blockIdx.x;
    const int b = bh >> 4, h = bh & 15;
    const int t = threadIdx.x;
    const int d = t & 63, seg = t >> 6;          // 4 segments of 512 keys
    const __fp16* Vh = (const __fp16*)V + (size_t)bh * HD * SEQ + (size_t)d * SEQ + seg * 512;
    float s = 0.f;
    for (int i = 0; i < 512; i += 8) {
        h8_t v = *(const h8_t*)(Vh + i);
#pragma unroll
        for (int j = 0; j < 8; j++) s += (float)v[j];
    }
    red[t] = s;
    __syncthreads();
    if (seg == 0) {
        float tot = red[d] + red[64 + d] + red[128 + d] + red[192 + d];
        O[(size_t)(b * SEQ + 2047) * D_MODEL + h * HD + d] = f2bf(tot * (1.f / 2048.f));
    }
}

extern "C" void kernel_launch(void* const* d_in, const int* in_sizes, int n_in,
                              void* d_out, int out_size, void* d_ws, size_t ws_size,
                              hipStream_t stream) {
    const float* x  = (const float*)d_in[0];
    const float* wq = (const float*)d_in[1];
    const float* wk = (const float*)d_in[2];
    const float* wv = (const float*)d_in[3];
    const float* wo = (const float*)d_in[4];

    const size_t elems = (size_t)BATCH * SEQ * D_MODEL;  // 8388608
    unsigned short* Qb = (unsigned short*)d_ws;          // bf16 [b,h,s,d]
    unsigned short* Kb = Qb + elems;                     // bf16 [b,h,s,d]
    unsigned short* Vb = Kb + elems;                     // f16  [b,h,d,s]
    unsigned short* Ob = Vb + elems;                     // bf16 [b,s,1024]

    dim3 g1(64, 8, 3);
    gemm_qkv_kernel<<<g1, 256, 0, stream>>>(x, wq, wk, wv, Qb, Kb, Vb);

    dim3 g2(32, BATCH * NH);
    attn_kernel<<<g2, 256, 0, stream>>>(Qb, Kb, Vb, Ob);

    row2047_kernel<<<BATCH * NH, 256, 0, stream>>>(Vb, Ob);

    dim3 g3(64, 8, 1);
    gemm_out_kernel<<<g3, 256, 0, stream>>>(Ob, wo, (float*)d_out);
}

// Round 5
// 333.944 us; speedup vs baseline: 1.4372x; 1.1739x over previous
//
#include <hip/hip_runtime.h>
#include <hip/hip_bf16.h>

typedef __attribute__((ext_vector_type(8))) short short8;
typedef __attribute__((ext_vector_type(4))) short bfx4;
typedef __attribute__((ext_vector_type(4))) float floatx4;
typedef __attribute__((ext_vector_type(4))) __fp16 h4_t;
typedef __attribute__((ext_vector_type(2))) __fp16 h2_t;
typedef __attribute__((ext_vector_type(8))) __fp16 h8_t;

#define BATCH 4
#define SEQ 2048
#define D_MODEL 1024
#define NH 16
#define HD 64
#define ELEMS 8388608   // B*S*D = 4*2048*1024
#define WELEMS 1048576  // 1024*1024

// fp32 -> bf16 round-to-nearest-even
__device__ __forceinline__ unsigned short f2bf(float f) {
    union { float f; unsigned u; } x; x.f = f;
    unsigned r = x.u + 0x7FFFu + ((x.u >> 16) & 1u);
    return (unsigned short)(r >> 16);
}
__device__ __forceinline__ unsigned short f2h(float f) {
    union { __fp16 h; unsigned short u; } x;
    x.h = (__fp16)f;
    return x.u;
}

// async global->LDS, 16B per lane; HW dest = wave-uniform base + lane*16
__device__ __forceinline__ void gll16(const void* g, const void* l) {
    __builtin_amdgcn_global_load_lds(
        (const __attribute__((address_space(1))) void*)g,
        (__attribute__((address_space(3))) void*)l,
        16, 0, 0);
}

// ---------------------------------------------------------------------------
// cvt: x (8M), wq|wk|wv (3M, concatenated), wo (1M) fp32 -> bf16
// ---------------------------------------------------------------------------
__global__ __launch_bounds__(256)
void cvt_kernel(const float* __restrict__ x,  const float* __restrict__ wq,
                const float* __restrict__ wk, const float* __restrict__ wv,
                const float* __restrict__ wo,
                unsigned short* __restrict__ xbf,
                unsigned short* __restrict__ wqkv,
                unsigned short* __restrict__ wobf)
{
    size_t idx = ((size_t)blockIdx.x * 256 + threadIdx.x) * 8;
    const float* src; unsigned short* dst; size_t off;
    if (idx < (size_t)ELEMS)                    { src = x;  dst = xbf;             off = idx; }
    else if (idx < (size_t)ELEMS + WELEMS)      { src = wq; dst = wqkv;            off = idx - ELEMS; }
    else if (idx < (size_t)ELEMS + 2 * WELEMS)  { src = wk; dst = wqkv + WELEMS;   off = idx - ELEMS - WELEMS; }
    else if (idx < (size_t)ELEMS + 3 * WELEMS)  { src = wv; dst = wqkv + 2*WELEMS; off = idx - ELEMS - 2*WELEMS; }
    else                                        { src = wo; dst = wobf;            off = idx - ELEMS - 3*WELEMS; }
    floatx4 a = *(const floatx4*)(src + off);
    floatx4 b = *(const floatx4*)(src + off + 4);
    short8 v;
#pragma unroll
    for (int d = 0; d < 4; d++) { v[d] = (short)f2bf(a[d]); v[4+d] = (short)f2bf(b[d]); }
    *(short8*)(dst + off) = v;
}

// ---------------------------------------------------------------------------
// Fast QKV GEMM: A=x_bf [8192,1024], B=wqkv_bf [3072,1024] (NT), both staged
// via global_load_lds with inverse-XOR-swizzled source addressing (the LDS
// ends up at slot row*8+(g^(row&7)) -> conflict-free ds_read_b128 fragments).
// 128x256 tile, BK=64. Epilogue scatters Q/K/V (z uniform per block).
// ---------------------------------------------------------------------------
__global__ __launch_bounds__(256, 2)
void gemm_qkv2_kernel(const unsigned short* __restrict__ A,
                      const unsigned short* __restrict__ B,
                      unsigned short* __restrict__ Qb,
                      unsigned short* __restrict__ Kb,
                      unsigned short* __restrict__ Vb)
{
    __shared__ __align__(16) unsigned short As[128 * 64];
    __shared__ __align__(16) unsigned short Bs[256 * 64];

    const int t = threadIdx.x;
    const int wave = t >> 6, lane = t & 63;
    const int lm = lane & 15, lq = lane >> 4;
    const int wrow = (wave >> 1) * 64, wcol = (wave & 1) * 128;
    const int m0 = blockIdx.x * 128, n0 = blockIdx.y * 256;
    const int lrow = lane >> 3, lg = lane & 7;
    const int gsw = lg ^ lrow;   // inverse-swizzle granule for 8-row issues

    floatx4 acc[4][8] = {};

    for (int k0 = 0; k0 < 1024; k0 += 64) {
        __syncthreads();
#pragma unroll
        for (int i = 0; i < 4; i++) {
            int rows8 = wave * 32 + i * 8;
            gll16(A + (size_t)(m0 + rows8 + lrow) * 1024 + k0 + gsw * 8, As + rows8 * 64);
        }
#pragma unroll
        for (int i = 0; i < 8; i++) {
            int rows8 = wave * 64 + i * 8;
            gll16(B + (size_t)(n0 + rows8 + lrow) * 1024 + k0 + gsw * 8, Bs + rows8 * 64);
        }
        __syncthreads();

#pragma unroll
        for (int c = 0; c < 2; c++) {
            short8 af[4], bfr[8];
#pragma unroll
            for (int i = 0; i < 4; i++) {
                int ra = wrow + i * 16 + lm;
                int g = c * 4 + lq;
                af[i] = *(const short8*)(As + (ra * 8 + (g ^ (ra & 7))) * 8);
            }
#pragma unroll
            for (int j = 0; j < 8; j++) {
                int rb = wcol + j * 16 + lm;
                int g = c * 4 + lq;
                bfr[j] = *(const short8*)(Bs + (rb * 8 + (g ^ (rb & 7))) * 8);
            }
#pragma unroll
            for (int i = 0; i < 4; i++)
#pragma unroll
                for (int j = 0; j < 8; j++)
                    acc[i][j] = __builtin_amdgcn_mfma_f32_16x16x32_bf16(
                        af[i], bfr[j], acc[i][j], 0, 0, 0);
        }
    }

    const int z = n0 >> 10;   // 0=Q 1=K 2=V, uniform per block
#pragma unroll
    for (int i = 0; i < 4; i++)
#pragma unroll
        for (int j = 0; j < 8; j++)
#pragma unroll
            for (int r = 0; r < 4; r++) {
                int gm = m0 + wrow + i * 16 + lq * 4 + r;
                int gn = n0 + wcol + j * 16 + lm;
                int nl = gn & 1023, h = nl >> 6, d = nl & 63;
                int b = gm >> 11, s = gm & 2047;
                float v = acc[i][j][r];
                size_t bh = (size_t)(b * NH + h);
                if (z == 0)      Qb[(bh * SEQ + s) * HD + d] = f2bf(v);
                else if (z == 1) Kb[(bh * SEQ + s) * HD + d] = f2bf(v);
                else             Vb[(bh * HD + d) * SEQ + s] = f2h(v);
            }
}

// ---------------------------------------------------------------------------
// Fast output projection: A=Ob bf16 [8192,1024], B=wo_bf [1024,1024] -> fp32
// ---------------------------------------------------------------------------
__global__ __launch_bounds__(256, 2)
void gemm_out2_kernel(const unsigned short* __restrict__ A,
                      const unsigned short* __restrict__ B,
                      float* __restrict__ Out)
{
    __shared__ __align__(16) unsigned short As[128 * 64];
    __shared__ __align__(16) unsigned short Bs[256 * 64];

    const int t = threadIdx.x;
    const int wave = t >> 6, lane = t & 63;
    const int lm = lane & 15, lq = lane >> 4;
    const int wrow = (wave >> 1) * 64, wcol = (wave & 1) * 128;
    const int m0 = blockIdx.x * 128, n0 = blockIdx.y * 256;
    const int lrow = lane >> 3, lg = lane & 7;
    const int gsw = lg ^ lrow;

    floatx4 acc[4][8] = {};

    for (int k0 = 0; k0 < 1024; k0 += 64) {
        __syncthreads();
#pragma unroll
        for (int i = 0; i < 4; i++) {
            int rows8 = wave * 32 + i * 8;
            gll16(A + (size_t)(m0 + rows8 + lrow) * 1024 + k0 + gsw * 8, As + rows8 * 64);
        }
#pragma unroll
        for (int i = 0; i < 8; i++) {
            int rows8 = wave * 64 + i * 8;
            gll16(B + (size_t)(n0 + rows8 + lrow) * 1024 + k0 + gsw * 8, Bs + rows8 * 64);
        }
        __syncthreads();

#pragma unroll
        for (int c = 0; c < 2; c++) {
            short8 af[4], bfr[8];
#pragma unroll
            for (int i = 0; i < 4; i++) {
                int ra = wrow + i * 16 + lm;
                int g = c * 4 + lq;
                af[i] = *(const short8*)(As + (ra * 8 + (g ^ (ra & 7))) * 8);
            }
#pragma unroll
            for (int j = 0; j < 8; j++) {
                int rb = wcol + j * 16 + lm;
                int g = c * 4 + lq;
                bfr[j] = *(const short8*)(Bs + (rb * 8 + (g ^ (rb & 7))) * 8);
            }
#pragma unroll
            for (int i = 0; i < 4; i++)
#pragma unroll
                for (int j = 0; j < 8; j++)
                    acc[i][j] = __builtin_amdgcn_mfma_f32_16x16x32_bf16(
                        af[i], bfr[j], acc[i][j], 0, 0, 0);
        }
    }

#pragma unroll
    for (int i = 0; i < 4; i++)
#pragma unroll
        for (int j = 0; j < 8; j++)
#pragma unroll
            for (int r = 0; r < 4; r++) {
                int gm = m0 + wrow + i * 16 + lq * 4 + r;
                int gn = n0 + wcol + j * 16 + lm;
                Out[(size_t)gm * D_MODEL + gn] = acc[i][j][r];
            }
}

// ---------------------------------------------------------------------------
// Flash attention v2: S^T formulation, 128-key tiles staged via
// global_load_lds (inverse swizzle), one online-softmax update per 128 keys.
// Inverted mask (keep kj > qi), scale folded into exponent. Tiles fully
// below the q-block are skipped (exp underflows to exact 0, matching fp32
// reference). Row 2047 fixed by row2047_kernel.
// Q,K bf16 [b,h,s,d]; V f16 [b,h,d,s]; O bf16 [b,s,1024].
// ---------------------------------------------------------------------------
__global__ __launch_bounds__(256, 4)
void attn2_kernel(const unsigned short* __restrict__ Q,
                  const unsigned short* __restrict__ K,
                  const unsigned short* __restrict__ V,
                  unsigned short* __restrict__ O)
{
    __shared__ __align__(16) unsigned short Ks[128 * 64];  // [key][d] swizzled bf16
    __shared__ __align__(16) unsigned short Vs[64 * 128];  // [d][key] swizzled f16

    const int t = threadIdx.x;
    const int wave = t >> 6, lane = t & 63;
    const int lm = lane & 15, lq = lane >> 4;
    const int bh = blockIdx.y, bx = blockIdx.x;
    const int qi = bx * 64 + wave * 16 + lm;

    const unsigned short* Qh = Q + (size_t)bh * SEQ * HD;
    const unsigned short* Kh = K + (size_t)bh * SEQ * HD;
    const unsigned short* Vh = V + (size_t)bh * HD * SEQ;  // [d][s]

    short8 bq[2];
    bq[0] = *(const short8*)(Qh + (size_t)qi * HD + lq * 8);
    bq[1] = *(const short8*)(Qh + (size_t)qi * HD + 32 + lq * 8);

    floatx4 acc[4] = {};   // O^T[d=jd*16+lq*4+r][q=lm]
    float m_run = -3.2e10f;  // unscaled fill = -1e9*32 (exact)
    float l_run = 0.f;
    const float kA = 0.04508422002778011f;  // log2(e)/32

    const int lrow = lane >> 3, lg = lane & 7;
    const int kt_last = bx >> 1;

    for (int kt = 15; kt >= kt_last; kt--) {
        __syncthreads();
        // K tile: 128 keys x 64 d (8 granules/row)
#pragma unroll
        for (int i = 0; i < 4; i++) {
            int rows8 = wave * 32 + i * 8;
            int g = lg ^ lrow;
            gll16(Kh + (size_t)(kt * 128 + rows8 + lrow) * HD + g * 8, Ks + rows8 * 64);
        }
        // V^T tile: 64 d x 128 keys (16 granules/row)
#pragma unroll
        for (int i = 0; i < 4; i++) {
            int rows4 = wave * 16 + i * 4;
            int row = rows4 + (lane >> 4);
            int g = (lane & 15) ^ (row & 15);
            gll16(Vh + (size_t)row * SEQ + kt * 128 + g * 8, Vs + rows4 * 128);
        }
        __syncthreads();

        // S^T[key][q] for 8 sub-blocks of 16 keys
        floatx4 sv[8];
#pragma unroll
        for (int jt = 0; jt < 8; jt++) {
            floatx4 sc = {};
#pragma unroll
            for (int c = 0; c < 2; c++) {
                int row = jt * 16 + lm;
                int g = c * 4 + lq;
                short8 kf = *(const short8*)(Ks + (row * 8 + (g ^ (row & 7))) * 8);
                sc = __builtin_amdgcn_mfma_f32_16x16x32_bf16(kf, bq[c], sc, 0, 0, 0);
            }
            sv[jt] = sc;
        }

        if (kt == kt_last) {  // wave-uniform; covers partial + dead sub-tile
#pragma unroll
            for (int jt = 0; jt < 8; jt++)
#pragma unroll
                for (int r = 0; r < 4; r++) {
                    int kj = kt * 128 + jt * 16 + lq * 4 + r;
                    if (!(kj > qi)) sv[jt][r] = -3.2e10f;
                }
        }

        // single online-softmax update per 128 keys
        float rm = -3.2e10f;
#pragma unroll
        for (int jt = 0; jt < 8; jt++)
#pragma unroll
            for (int r = 0; r < 4; r++) rm = fmaxf(rm, sv[jt][r]);
        rm = fmaxf(rm, __shfl_xor(rm, 16));
        rm = fmaxf(rm, __shfl_xor(rm, 32));

        float mnew = fmaxf(m_run, rm);
        float alpha = exp2f((m_run - mnew) * kA);
        m_run = mnew;

        float rs = 0.f;
#pragma unroll
        for (int jt = 0; jt < 8; jt++)
#pragma unroll
            for (int r = 0; r < 4; r++) {
                float p = exp2f((sv[jt][r] - mnew) * kA);
                sv[jt][r] = p;
                rs += p;
            }
        rs += __shfl_xor(rs, 16);
        rs += __shfl_xor(rs, 32);
        l_run = l_run * alpha + rs;

#pragma unroll
        for (int jd = 0; jd < 4; jd++)
#pragma unroll
            for (int r = 0; r < 4; r++) acc[jd][r] *= alpha;

        // PV: O^T[d][q] += V^T[d][key] * P^T[key][q] (P^T direct from regs)
#pragma unroll
        for (int jt = 0; jt < 8; jt++) {
            h2_t p01 = __builtin_amdgcn_cvt_pkrtz(sv[jt][0], sv[jt][1]);
            h2_t p23 = __builtin_amdgcn_cvt_pkrtz(sv[jt][2], sv[jt][3]);
            h4_t pf;
            pf[0] = p01[0]; pf[1] = p01[1]; pf[2] = p23[0]; pf[3] = p23[1];
#pragma unroll
            for (int jd = 0; jd < 4; jd++) {
                int rowv = jd * 16 + lm;
                int g16 = jt * 2 + (lq >> 1);
                int slot = rowv * 16 + (g16 ^ lm);   // rowv&15 == lm
                h4_t vf = *(const h4_t*)((const __fp16*)Vs + slot * 8 + (lq & 1) * 4);
                acc[jd] = __builtin_amdgcn_mfma_f32_16x16x16f16(vf, pf, acc[jd], 0, 0, 0);
            }
        }
    }

    const int b = bh >> 4, h = bh & 15;
    float inv = 1.0f / l_run;
#pragma unroll
    for (int jd = 0; jd < 4; jd++) {
        bfx4 o;
#pragma unroll
        for (int r = 0; r < 4; r++) o[r] = (short)f2bf(acc[jd][r] * inv);
        *(bfx4*)(O + (size_t)(b * SEQ + qi) * D_MODEL + h * HD + jd * 16 + lq * 4) = o;
    }
}

// ---------------------------------------------------------------------------
// Row 2047 is fully masked -> uniform softmax over ALL keys -> mean of V.
// ---------------------------------------------------------------------------
__global__ __launch_bounds__(256, 2)
void row2047_kernel(const unsigned short* __restrict__ V,
                    unsigned short* __restrict__ O)
{
    __shared__ float red[256];
    const int bh = blockIdx.x;
    const int b = bh >> 4, h = bh & 15;
    const int t = threadIdx.x;
    const int d = t & 63, seg = t >> 6;
    const __fp16* Vh = (const __fp16*)V + (size_t)bh * HD * SEQ + (size_t)d * SEQ + seg * 512;
    float s = 0.f;
    for (int i = 0; i < 512; i += 8) {
        h8_t v = *(const h8_t*)(Vh + i);
#pragma unroll
        for (int j = 0; j < 8; j++) s += (float)v[j];
    }
    red[t] = s;
    __syncthreads();
    if (seg == 0) {
        float tot = red[d] + red[64 + d] + red[128 + d] + red[192 + d];
        O[(size_t)(b * SEQ + 2047) * D_MODEL + h * HD + d] = f2bf(tot * (1.f / 2048.f));
    }
}

// ======================= fallback (ws < 72 MiB) kernels =====================
__global__ __launch_bounds__(256, 2)
void gemm_qkv_kernel(const float* __restrict__ A,
                     const float* __restrict__ W0,
                     const float* __restrict__ W1,
                     const float* __restrict__ W2,
                     unsigned short* __restrict__ O0,
                     unsigned short* __restrict__ O1,
                     unsigned short* __restrict__ O2)
{
    const int K = 1024;
    const float* W;
    unsigned short* Out;
    if (blockIdx.z == 0)      { W = W0; Out = O0; }
    else if (blockIdx.z == 1) { W = W1; Out = O1; }
    else                      { W = W2; Out = O2; }

    __shared__ __align__(16) unsigned short As[128 * 64];
    __shared__ __align__(16) unsigned short Bs[128 * 64];

    const int t = threadIdx.x;
    const int wave = t >> 6, lane = t & 63;
    const int lm = lane & 15, lq = lane >> 4;
    const int wrow = (wave >> 1) * 64, wcol = (wave & 1) * 64;
    const int m0 = blockIdx.x * 128, n0 = blockIdx.y * 128;

    floatx4 acc[4][4] = {};

    for (int k0 = 0; k0 < K; k0 += 64) {
        __syncthreads();
#pragma unroll
        for (int rr = 0; rr < 4; rr++) {
            int p = rr * 256 + t;
            int row = p >> 3, g = p & 7;
            const float* pa = A + (size_t)(m0 + row) * K + k0 + g * 8;
            const float* pw = W + (size_t)(n0 + row) * K + k0 + g * 8;
            floatx4 a0 = *(const floatx4*)pa, a1 = *(const floatx4*)(pa + 4);
            floatx4 w0 = *(const floatx4*)pw, w1 = *(const floatx4*)(pw + 4);
            short8 va, vb;
#pragma unroll
            for (int d = 0; d < 4; d++) {
                va[d]     = (short)f2bf(a0[d]);
                va[4 + d] = (short)f2bf(a1[d]);
                vb[d]     = (short)f2bf(w0[d]);
                vb[4 + d] = (short)f2bf(w1[d]);
            }
            int dst = row * 8 + (g ^ (row & 7));
            *(short8*)(As + dst * 8) = va;
            *(short8*)(Bs + dst * 8) = vb;
        }
        __syncthreads();

        short8 af[4][2], bf[4][2];
#pragma unroll
        for (int i = 0; i < 4; i++)
#pragma unroll
            for (int c = 0; c < 2; c++) {
                int ra = wrow + i * 16 + lm;
                int rb = wcol + i * 16 + lm;
                int g = c * 4 + lq;
                af[i][c] = *(const short8*)(As + (ra * 8 + (g ^ (ra & 7))) * 8);
                bf[i][c] = *(const short8*)(Bs + (rb * 8 + (g ^ (rb & 7))) * 8);
            }
#pragma unroll
        for (int i = 0; i < 4; i++)
#pragma unroll
            for (int j = 0; j < 4; j++)
#pragma unroll
                for (int c = 0; c < 2; c++)
                    acc[i][j] = __builtin_amdgcn_mfma_f32_16x16x32_bf16(
                        af[i][c], bf[j][c], acc[i][j], 0, 0, 0);
    }

    const int zi = blockIdx.z;
#pragma unroll
    for (int i = 0; i < 4; i++)
#pragma unroll
        for (int j = 0; j < 4; j++)
#pragma unroll
            for (int r = 0; r < 4; r++) {
                int gm = m0 + wrow + i * 16 + lq * 4 + r;
                int gn = n0 + wcol + j * 16 + lm;
                int b = gm >> 11, s = gm & 2047;
                int h = gn >> 6, d = gn & 63;
                if (zi == 2) {
                    Out[((size_t)(b * NH + h) * HD + d) * SEQ + s] = f2h(acc[i][j][r]);
                } else {
                    Out[((size_t)(b * NH + h) * SEQ + s) * HD + d] = f2bf(acc[i][j][r]);
                }
            }
}

__global__ __launch_bounds__(256, 2)
void gemm_out_kernel(const unsigned short* __restrict__ Abf,
                     const float* __restrict__ W,
                     float* __restrict__ Out)
{
    const int K = 1024;
    __shared__ __align__(16) unsigned short As[128 * 64];
    __shared__ __align__(16) unsigned short Bs[128 * 64];

    const int t = threadIdx.x;
    const int wave = t >> 6, lane = t & 63;
    const int lm = lane & 15, lq = lane >> 4;
    const int wrow = (wave >> 1) * 64, wcol = (wave & 1) * 64;
    const int m0 = blockIdx.x * 128, n0 = blockIdx.y * 128;

    floatx4 acc[4][4] = {};

    for (int k0 = 0; k0 < K; k0 += 64) {
        __syncthreads();
#pragma unroll
        for (int rr = 0; rr < 4; rr++) {
            int p = rr * 256 + t;
            int row = p >> 3, g = p & 7;
            short8 va = *(const short8*)(Abf + (size_t)(m0 + row) * K + k0 + g * 8);
            const float* pw = W + (size_t)(n0 + row) * K + k0 + g * 8;
            floatx4 w0 = *(const floatx4*)pw, w1 = *(const floatx4*)(pw + 4);
            short8 vb;
#pragma unroll
            for (int d = 0; d < 4; d++) {
                vb[d]     = (short)f2bf(w0[d]);
                vb[4 + d] = (short)f2bf(w1[d]);
            }
            int dst = row * 8 + (g ^ (row & 7));
            *(short8*)(As + dst * 8) = va;
            *(short8*)(Bs + dst * 8) = vb;
        }
        __syncthreads();

        short8 af[4][2], bf[4][2];
#pragma unroll
        for (int i = 0; i < 4; i++)
#pragma unroll
            for (int c = 0; c < 2; c++) {
                int ra = wrow + i * 16 + lm;
                int rb = wcol + i * 16 + lm;
                int g = c * 4 + lq;
                af[i][c] = *(const short8*)(As + (ra * 8 + (g ^ (ra & 7))) * 8);
                bf[i][c] = *(const short8*)(Bs + (rb * 8 + (g ^ (rb & 7))) * 8);
            }
#pragma unroll
        for (int i = 0; i < 4; i++)
#pragma unroll
            for (int j = 0; j < 4; j++)
#pragma unroll
                for (int c = 0; c < 2; c++)
                    acc[i][j] = __builtin_amdgcn_mfma_f32_16x16x32_bf16(
                        af[i][c], bf[j][c], acc[i][j], 0, 0, 0);
    }

#pragma unroll
    for (int i = 0; i < 4; i++)
#pragma unroll
        for (int j = 0; j < 4; j++)
#pragma unroll
            for (int r = 0; r < 4; r++) {
                int gm = m0 + wrow + i * 16 + lq * 4 + r;
                int gn = n0 + wcol + j * 16 + lm;
                Out[(size_t)gm * D_MODEL + gn] = acc[i][j][r];
            }
}

extern "C" void kernel_launch(void* const* d_in, const int* in_sizes, int n_in,
                              void* d_out, int out_size, void* d_ws, size_t ws_size,
                              hipStream_t stream) {
    const float* x  = (const float*)d_in[0];
    const float* wq = (const float*)d_in[1];
    const float* wk = (const float*)d_in[2];
    const float* wv = (const float*)d_in[3];
    const float* wo = (const float*)d_in[4];

    unsigned short* ws = (unsigned short*)d_ws;
    const bool fast = ws_size >= (size_t)36 * 1024 * 1024 * 2;  // 72 MiB

    if (fast) {
        unsigned short* xbf  = ws;                     // 8M elems; reused as Ob
        unsigned short* wqkv = ws + (size_t)ELEMS;     // 3M
        unsigned short* wobf = ws + (size_t)ELEMS + 3 * WELEMS;  // 1M
        unsigned short* Qb   = ws + (size_t)ELEMS + 4 * WELEMS;  // 8M
        unsigned short* Kb   = Qb + ELEMS;
        unsigned short* Vb   = Kb + ELEMS;
        unsigned short* Ob   = xbf;                    // x_bf dead after QKV GEMM

        cvt_kernel<<<6144, 256, 0, stream>>>(x, wq, wk, wv, wo, xbf, wqkv, wobf);
        gemm_qkv2_kernel<<<dim3(64, 12), 256, 0, stream>>>(xbf, wqkv, Qb, Kb, Vb);
        attn2_kernel<<<dim3(32, BATCH * NH), 256, 0, stream>>>(Qb, Kb, Vb, Ob);
        row2047_kernel<<<BATCH * NH, 256, 0, stream>>>(Vb, Ob);
        gemm_out2_kernel<<<dim3(64, 4), 256, 0, stream>>>(Ob, wobf, (float*)d_out);
    } else {
        unsigned short* Qb = ws;
        unsigned short* Kb = Qb + ELEMS;
        unsigned short* Vb = Kb + ELEMS;
        unsigned short* Ob = Vb + ELEMS;

        gemm_qkv_kernel<<<dim3(64, 8, 3), 256, 0, stream>>>(x, wq, wk, wv, Qb, Kb, Vb);
        attn2_kernel<<<dim3(32, BATCH * NH), 256, 0, stream>>>(Qb, Kb, Vb, Ob);
        row2047_kernel<<<BATCH * NH, 256, 0, stream>>>(Vb, Ob);
        gemm_out_kernel<<<dim3(64, 8), 256, 0, stream>>>(Ob, wo, (float*)d_out);
    }
}